// Round 9
// baseline (173.768 us; speedup 1.0000x reference)
//
#include <hip/hip_runtime.h>
#include <hip/hip_bf16.h>

// Locally-connected conv, ALL FP32 in/out, bf16 MFMA compute.
//   x:   (32, 16, 64, 64)        float
//   w:   (60, 60, 16, 5, 5, 16)  float   (per-position 400x16, k innermost)
//   out: (32, 16, 60, 60)        float
//
// Round-9: barrier-free streaming pipeline (r6-r8 lesson: any kernel coupling
// the W stream to a __syncthreads drain gets ~35-60% duty cycle).
//  * prep: w -> wt[pos][cc][q][l15][jj] bf16 (MFMA-B fragment order, 48 MB)
//    via 26 independent L1-hit dword gathers/thread (block set = 25.6 KB);
//    coalesced dword writes; no LDS, no barrier. Fused: make_xc blocks.
//  * lc_main: 1 wave/position, NO LDS, NO barrier: B-frag = one contiguous
//    16B load from wt (1 KB/wave-instr, L3-hot), A-frags = r7-proven xc
//    loads, 26 MFMA, packed ws store.
//  * transpose_out epilogue (proven, keeps WRITE at 1x).

#define OUT_HW 60
#define IN_HW  64
#define CIN    16
#define COUT   16
#define NPOS   3600              // OUT_HW*OUT_HW
#define BK     512               // NB*COUT
#define WT_POS 6656              // bf16 elements per position = 13*512
#define XC_ELE (32u * 64u * 64u * 16u)   // 2,097,152 bf16 elements

typedef __attribute__((ext_vector_type(8))) short bf16x8;
typedef __attribute__((ext_vector_type(4))) float f32x4;

static __device__ __forceinline__ unsigned pk2(float a, float b) {
    union { __hip_bfloat162 h; unsigned u; } cv;
    cv.h = __float22bfloat162_rn(make_float2(a, b));
    return cv.u;
}

// ---- prep: blocks [0,NPOS): W transpose to fragment order;
//            blocks [NPOS, NPOS+2048): xc[b][h][w][c] bf16 <- x (r5-r8 proven)
__global__ __launch_bounds__(256)
void prep(const float* __restrict__ x, const float* __restrict__ w,
          ushort* __restrict__ xc, ushort* __restrict__ wt) {
    const int bid = blockIdx.x;
    const int t = threadIdx.x;
    if (bid < NPOS) {
        const float* wbase = w + (size_t)bid * 6400;
        unsigned* dstd = (unsigned*)(wt + (size_t)bid * WT_POS);
#pragma unroll
        for (int it = 0; it < 13; ++it) {
            const int d = it * 256 + t;          // dword index, 3328/pos
            const int e = d * 2;                 // element; jj even
            const int cc  = e >> 9;
            const int q   = (e >> 7) & 3;
            const int l15 = (e >> 3) & 15;
            const int jj  = e & 7;
            const int uvB = cc * 2 + (q >> 1);
            const int c0  = (q & 1) << 3;
            unsigned val = 0u;                   // K-pad (uv=25) = 0
            if (uvB < 25) {                      // wave-uniform branch
                const int m0 = (c0 + jj) * 25 + uvB;
                val = pk2(wbase[m0 * 16 + l15],          // (c0+jj,   uvB, k=l15)
                          wbase[(m0 + 25) * 16 + l15]);  // (c0+jj+1, uvB, k=l15)
            }
            dstd[d] = val;                       // coalesced 1 KB/wave-instr
        }
    } else {
        const int bh = bid - NPOS;               // b*64 + h
        const int b = bh >> 6, h = bh & 63;
        const int cq = t & 3, wc = t >> 2;
        const float* src = x + ((size_t)(b * CIN) * IN_HW + h) * IN_HW + wc;
        float f[4];
#pragma unroll
        for (int e = 0; e < 4; ++e)
            f[e] = src[(size_t)(cq * 4 + e) * (IN_HW * IN_HW)];
        union { ushort4 v; unsigned u[2]; } o;
        o.u[0] = pk2(f[0], f[1]);
        o.u[1] = pk2(f[2], f[3]);
        *(ushort4*)&xc[((size_t)bh * IN_HW + wc) * CIN + cq * 4] = o.v;
    }
}

// ---- main: one wave per position; no LDS, no barriers ----
__global__ __launch_bounds__(64)
void lc_main(const ushort* __restrict__ xc, const ushort* __restrict__ wt,
             float* __restrict__ dst) {
    const int bid = blockIdx.x;
    const int pos = (bid & 7) * 450 + (bid >> 3);   // XCD swizzle (bijective)
    const int i = pos / OUT_HW, j = pos - i * OUT_HW;
    const int lane = threadIdx.x;
    const int l15 = lane & 15, q = lane >> 4;
    const int qh = q >> 1, c0 = (q & 1) << 3;

    const ushort* wtp = wt + (size_t)pos * WT_POS + q * 128 + l15 * 8;
    const int base_hw = i * IN_HW + j;
    const size_t bofs0 = (size_t)l15 * (IN_HW * IN_HW * CIN);        // b = l15
    const size_t bofs1 = (size_t)(l15 + 16) * (IN_HW * IN_HW * CIN); // b + 16

    f32x4 acc0 = {0.f, 0.f, 0.f, 0.f}, acc1 = {0.f, 0.f, 0.f, 0.f};
#pragma unroll
    for (int cc = 0; cc < 13; ++cc) {
        const int uvB = cc * 2 + qh;
        const int uvA = (uvB < 25) ? uvB : 24;      // clamp; wt is 0 there
        const int uA = (uvA * 13) >> 6;             // uv/5 for uv<=24
        const int vA = uvA - 5 * uA;
        const size_t xo = (size_t)(base_hw + uA * IN_HW + vA) * CIN + c0;
        const bf16x8 bF = *(const bf16x8*)(wtp + cc * 512);   // contiguous 16B
        const bf16x8 a0 = *(const bf16x8*)(xc + bofs0 + xo);
        const bf16x8 a1 = *(const bf16x8*)(xc + bofs1 + xo);
        acc0 = __builtin_amdgcn_mfma_f32_16x16x32_bf16(a0, bF, acc0, 0, 0, 0);
        acc1 = __builtin_amdgcn_mfma_f32_16x16x32_bf16(a1, bF, acc1, 0, 0, 0);
    }

    // packed ws[pos][bk]: wave writes its full 2 KB block
#pragma unroll
    for (int r = 0; r < 4; ++r) {
        dst[(size_t)pos * BK + (q * 4 + r) * 16 + l15]        = acc0[r];
        dst[(size_t)pos * BK + (q * 4 + r + 16) * 16 + l15]   = acc1[r];
    }
}

// ---- epilogue: ws[oij][bk] -> out[bk][oij] (proven r3..r6) ----
__global__ __launch_bounds__(256)
void transpose_out(const float* __restrict__ src, float* __restrict__ out) {
    __shared__ float tile[64][65];
    const int o0 = blockIdx.x * 64;
    const int k0 = blockIdx.y * 64;
    const int t  = threadIdx.x;
    const int tx = t & 63, ty = t >> 6;
    for (int r = ty; r < 64; r += 4) {
        const int oij = o0 + r;
        if (oij < NPOS) tile[r][tx] = src[(size_t)oij * BK + k0 + tx];
    }
    __syncthreads();
    for (int r = ty; r < 64; r += 4) {
        const int oij = o0 + tx;
        if (oij < NPOS) out[(size_t)(k0 + r) * NPOS + oij] = tile[tx][r];
    }
}

// ---- emergency fallback (ws too small): naive, correct, slow ----
__global__ __launch_bounds__(256)
void lc_naive(const float* __restrict__ x, const float* __restrict__ w,
              float* __restrict__ out) {
    const int gid = blockIdx.x * 256 + threadIdx.x;
    if (gid >= 32 * COUT * NPOS) return;
    const int j = gid % OUT_HW;
    int rest = gid / OUT_HW;
    const int i = rest % OUT_HW; rest /= OUT_HW;
    const int k = rest % COUT;
    const int b = rest / COUT;
    const float* wp = w + (size_t)(i * OUT_HW + j) * 6400 + k;
    float s = 0.f;
    for (int c = 0; c < CIN; ++c)
        for (int u = 0; u < 5; ++u)
            for (int v = 0; v < 5; ++v)
                s += x[((size_t)(b * CIN + c) * IN_HW + i + u) * IN_HW + j + v]
                   * wp[((c * 5 + u) * 5 + v) * COUT];
    out[gid] = s;
}

extern "C" void kernel_launch(void* const* d_in, const int* in_sizes, int n_in,
                              void* d_out, int out_size, void* d_ws, size_t ws_size,
                              hipStream_t stream) {
    const float* x = (const float*)d_in[0];
    const float* w = (const float*)d_in[1];
    float* out = (float*)d_out;

    const size_t xcBytes  = (size_t)XC_ELE * 2;            //  4,194,304
    const size_t outBytes = (size_t)NPOS * BK * 4;         //  7,372,800
    const size_t wtBytes  = (size_t)NPOS * WT_POS * 2;     // 47,923,200

    if (ws_size >= xcBytes + outBytes + wtBytes) {
        ushort* xc    = (ushort*)d_ws;
        float*  wsOut = (float*)((char*)d_ws + xcBytes);
        ushort* wtp   = (ushort*)((char*)d_ws + xcBytes + outBytes);
        prep<<<NPOS + 2048, 256, 0, stream>>>(x, w, xc, wtp);
        lc_main<<<NPOS, 64, 0, stream>>>(xc, wtp, wsOut);
        transpose_out<<<dim3((NPOS + 63) / 64, BK / 64), 256, 0, stream>>>(wsOut, out);
    } else {
        lc_naive<<<(32 * COUT * NPOS + 255) / 256, 256, 0, stream>>>(x, w, out);
    }
}

// Round 10
// 159.825 us; speedup vs baseline: 1.0872x; 1.0872x over previous
//
#include <hip/hip_runtime.h>
#include <hip/hip_bf16.h>

// Locally-connected conv, ALL FP32 in/out, bf16 MFMA compute.
//   x:   (32, 16, 64, 64)        float
//   w:   (60, 60, 16, 5, 5, 16)  float   (per-position 400x16, k innermost)
//   out: (32, 16, 60, 60)        float
//
// Round-10 = round-6 winner (155.1 us) + ONE change: dense A-layout
// xc2[h][w][b][c] (was [b][h][w][c]). r6's A-loads had lanes strided 128 KB
// -> ~32 L2 lines/instr, 16B used per 64B line (4x L2 inflation inside the
// barrier drain). With [h][w][b][c], one A-instr = two dense 512B regions,
// every fetched byte used.
//  * W staged via __builtin_amdgcn_global_load_lds width=16 (no scratch).
//  * K-split 4 waves, A-prefetch before barrier, sRed reduce (r6-proven).
//  * packed ws store + transpose_out epilogue (r3..r6-proven).

#define OUT_HW 60
#define IN_HW  64
#define CIN    16
#define COUT   16
#define NPOS   3600              // OUT_HW*OUT_HW
#define BK     512               // NB*COUT
#define HWSTR  512               // xc2 elements per (h,w): 32 b * 16 c
#define XC_ELE (64u * 64u * 32u * 16u)   // 2,097,152 bf16 elements

typedef __attribute__((ext_vector_type(8))) short bf16x8;
typedef __attribute__((ext_vector_type(4))) float f32x4;

static __device__ __forceinline__ unsigned pk2(float a, float b) {
    union { __hip_bfloat162 h; unsigned u; } cv;
    cv.h = __float22bfloat162_rn(make_float2(a, b));
    return cv.u;
}

// async global->LDS, 16B per lane; LDS dest wave-uniform, src per-lane.
static __device__ __forceinline__ void g2lds16(const float* g, float* l) {
    __builtin_amdgcn_global_load_lds(
        (const __attribute__((address_space(1))) unsigned int*)g,
        (__attribute__((address_space(3))) unsigned int*)l, 16, 0, 0);
}

// ---- prepass: xc2[h][w][b][c] bf16 <- x[b][c][h][w] fp32 ----
// Reads: lanes span w -> 256B coalesced per (b,c). Writes: 32B/lane, block
// working set 64KB -> L2 merges lines before eviction.
__global__ __launch_bounds__(256)
void make_xc2(const float* __restrict__ x, ushort* __restrict__ xc2) {
    const int h = blockIdx.x;                // 0..63
    const int t = threadIdx.x;
    const int wj = t & 63;
#pragma unroll
    for (int it = 0; it < 8; ++it) {
        const int b = (t >> 6) + it * 4;     // 0..31
        const float* src = x + ((size_t)(b * CIN) * IN_HW + h) * IN_HW + wj;
        float f[16];
#pragma unroll
        for (int c = 0; c < 16; ++c)
            f[c] = src[(size_t)c * (IN_HW * IN_HW)];
        union { ushort v[16]; uint4 u[2]; } o;
#pragma unroll
        for (int e = 0; e < 8; ++e)
            ((unsigned*)o.v)[e] = pk2(f[2 * e], f[2 * e + 1]);
        uint4* dst = (uint4*)&xc2[((size_t)(h * IN_HW + wj) * 32 + b) * 16];
        dst[0] = o.u[0];
        dst[1] = o.u[1];
    }
}

// ---- main: one block (256 thr, 4 K-split waves) per output position ----
template<int PACKED>
__global__ __launch_bounds__(256, 4)
void lc_pos(const ushort* __restrict__ xc2, const float* __restrict__ w,
            float* __restrict__ dst) {
    __shared__ float sWraw[6400] __attribute__((aligned(16)));  // raw [m][k], 25,600 B
    __shared__ float sRed[4][32 * 17];                          //  8,704 B

    const int bid = blockIdx.x;
    const int pos = (bid & 7) * 450 + (bid >> 3);   // XCD swizzle (bijective)
    const int i = pos / OUT_HW, j = pos - i * OUT_HW;
    const int t = threadIdx.x;
    const int lane = t & 63, wv = t >> 6;
    const int l15 = lane & 15, q = lane >> 4;
    const int qh = q >> 1, c0 = (q & 1) << 3;

    // ---- W: async DMA, 25 x (64 lanes x 16B) = 25,600 B, raw load order ----
    const float* wsrc = w + (size_t)pos * 6400 + lane * 4;
    for (int o = wv; o < 25; o += 4)
        g2lds16(wsrc + o * 256, &sWraw[o * 256]);

    // ---- X: prefetch A-fragments, DENSE layout (overlaps the W DMA) ----
    const int base_hw = i * IN_HW + j;
    bf16x8 xa0[4], xa1[4];
#pragma unroll
    for (int it = 0; it < 4; ++it) {
        const int cc = wv + it * 4;
        if (cc < 13) {
            const int uvB = cc * 2 + qh;
            const int uvA = (uvB < 25) ? uvB : 24;   // clamped; W=0 there
            const int uA = (uvA * 13) >> 6;          // uv/5 for uv<=24
            const int vA = uvA - 5 * uA;
            const ushort* p = xc2
                + (size_t)(base_hw + uA * IN_HW + vA) * HWSTR + l15 * 16 + c0;
            xa0[it] = *(const bf16x8*)(p);           // b = l15
            xa1[it] = *(const bf16x8*)(p + 256);     // b = l15 + 16
        }
    }

    __syncthreads();   // drains DMA + prefetch (vmcnt), then barrier

    // ---- MFMA: k_r=(uv,c), c innermost; wave wv does chunks {wv, wv+4, ...} ----
    f32x4 acc0 = {0.f, 0.f, 0.f, 0.f}, acc1 = {0.f, 0.f, 0.f, 0.f};
#pragma unroll
    for (int it = 0; it < 4; ++it) {
        const int cc = wv + it * 4;
        if (cc < 13) {
            const int uvB = cc * 2 + qh;
            const int okB = (uvB < 25);
            float bfv[8];
#pragma unroll
            for (int jj = 0; jj < 8; ++jj)      // m = (c0+jj)*25 + uvB, k = l15
                bfv[jj] = okB ? sWraw[(c0 + jj) * 400 + uvB * 16 + l15] : 0.f;
            union { bf16x8 v; unsigned u[4]; } pb;
#pragma unroll
            for (int jj = 0; jj < 4; ++jj) pb.u[jj] = pk2(bfv[2 * jj], bfv[2 * jj + 1]);
            acc0 = __builtin_amdgcn_mfma_f32_16x16x32_bf16(xa0[it], pb.v, acc0, 0, 0, 0);
            acc1 = __builtin_amdgcn_mfma_f32_16x16x32_bf16(xa1[it], pb.v, acc1, 0, 0, 0);
        }
    }

    // ---- K-split reduce (r4/r6-proven pattern) ----
#pragma unroll
    for (int r = 0; r < 4; ++r) {
        sRed[wv][(q * 4 + r) * 17 + l15]      = acc0[r];   // D rows b = q*4+r
        sRed[wv][(q * 4 + r + 16) * 17 + l15] = acc1[r];   // b + 16
    }
    __syncthreads();
#pragma unroll
    for (int h = 0; h < 2; ++h) {
        const int o = t + h * 256;                  // o = b*16 + k
        const int idx = (o >> 4) * 17 + (o & 15);
        const float sv = sRed[0][idx] + sRed[1][idx] + sRed[2][idx] + sRed[3][idx];
        if (PACKED) dst[(size_t)pos * BK + o] = sv;        // ws[oij][bk]
        else        dst[(size_t)o * NPOS + pos] = sv;      // scattered fallback
    }
}

// ---- epilogue: ws[oij][bk] -> out[bk][oij] (proven r3..r6) ----
__global__ __launch_bounds__(256)
void transpose_out(const float* __restrict__ src, float* __restrict__ out) {
    __shared__ float tile[64][65];
    const int o0 = blockIdx.x * 64;
    const int k0 = blockIdx.y * 64;
    const int t  = threadIdx.x;
    const int tx = t & 63, ty = t >> 6;
    for (int r = ty; r < 64; r += 4) {
        const int oij = o0 + r;
        if (oij < NPOS) tile[r][tx] = src[(size_t)oij * BK + k0 + tx];
    }
    __syncthreads();
    for (int r = ty; r < 64; r += 4) {
        const int oij = o0 + tx;
        if (oij < NPOS) out[(size_t)(k0 + r) * NPOS + oij] = tile[tx][r];
    }
}

// ---- emergency fallback (ws too small): naive, correct, slow ----
__global__ __launch_bounds__(256)
void lc_naive(const float* __restrict__ x, const float* __restrict__ w,
              float* __restrict__ out) {
    const int gid = blockIdx.x * 256 + threadIdx.x;
    if (gid >= 32 * COUT * NPOS) return;
    const int j = gid % OUT_HW;
    int rest = gid / OUT_HW;
    const int i = rest % OUT_HW; rest /= OUT_HW;
    const int k = rest % COUT;
    const int b = rest / COUT;
    const float* wp = w + (size_t)(i * OUT_HW + j) * 6400 + k;
    float s = 0.f;
    for (int c = 0; c < CIN; ++c)
        for (int u = 0; u < 5; ++u)
            for (int v = 0; v < 5; ++v)
                s += x[((size_t)(b * CIN + c) * IN_HW + i + u) * IN_HW + j + v]
                   * wp[((c * 5 + u) * 5 + v) * COUT];
    out[gid] = s;
}

extern "C" void kernel_launch(void* const* d_in, const int* in_sizes, int n_in,
                              void* d_out, int out_size, void* d_ws, size_t ws_size,
                              hipStream_t stream) {
    const float* x = (const float*)d_in[0];
    const float* w = (const float*)d_in[1];
    float* out = (float*)d_out;

    const size_t xcBytes  = (size_t)XC_ELE * 2;        // 4,194,304
    const size_t outBytes = (size_t)NPOS * BK * 4;     // 7,372,800
    ushort* xc2 = (ushort*)d_ws;

    if (ws_size >= xcBytes + outBytes) {
        float* wsOut = (float*)((char*)d_ws + xcBytes);
        make_xc2<<<IN_HW, 256, 0, stream>>>(x, xc2);
        lc_pos<1><<<NPOS, 256, 0, stream>>>(xc2, w, wsOut);
        transpose_out<<<dim3((NPOS + 63) / 64, BK / 64), 256, 0, stream>>>(wsOut, out);
    } else if (ws_size >= xcBytes) {
        make_xc2<<<IN_HW, 256, 0, stream>>>(x, xc2);
        lc_pos<0><<<NPOS, 256, 0, stream>>>(xc2, w, out);
    } else {
        lc_naive<<<(32 * COUT * NPOS + 255) / 256, 256, 0, stream>>>(x, w, out);
    }
}